// Round 17
// baseline (406.692 us; speedup 1.0000x reference)
//
#include <hip/hip_runtime.h>
#include <hip/hip_bf16.h>

#define LNUM 4
#define DIM  512
#define SS   256

typedef unsigned short ushort_t;
typedef __attribute__((ext_vector_type(8))) short bf16x8;
typedef __attribute__((ext_vector_type(4))) float f32x4;
typedef __attribute__((ext_vector_type(8))) unsigned short u16x8;

#define VWAIT(n) asm volatile("s_waitcnt vmcnt(" #n ")" ::: "memory")
__device__ __forceinline__ void bar() { __builtin_amdgcn_s_barrier(); }

__device__ __forceinline__ ushort_t f2b(float f) {
  union { float f; unsigned u; } x; x.f = f;
  unsigned r = x.u + 0x7FFFu + ((x.u >> 16) & 1u);
  return (ushort_t)(r >> 16);
}

__device__ __forceinline__ void gload16(const void* g, void* s) {
  __builtin_amdgcn_global_load_lds((const __attribute__((address_space(1))) void*)g,
                                   (__attribute__((address_space(3))) void*)s, 16, 0, 0);
}

// ---------------------------------------------------------------------------
// C = A * B^T. NBUF=3: depth-2 prefetch, counted vmcnt. NBUF=2: 2-phase
// double-buffer (only for tiles whose grid keeps >=2 blocks/CU).
// EPI 0: outB = bf16(acc + bias) [relu opt]
// EPI 2: outF[kz partial] = acc + bias(kz==0)   (split-K fp32 stores)
// EPI 3: fused QKV routing; Q,K head-major [bh][s][dk]; V repacked -> vT
// ---------------------------------------------------------------------------
template<int TM, int TN, int EPI, int NBUF>
__global__ __launch_bounds__(256, 2)
void gemm_bt(const ushort_t* __restrict__ A, const ushort_t* __restrict__ B,
             const float* __restrict__ bias, const float* __restrict__ bias2,
             const float* __restrict__ bias3,
             ushort_t* __restrict__ outB, ushort_t* __restrict__ outB2,
             ushort_t* __restrict__ outB3, float* __restrict__ outF,
             int K, int lda, int ldb, int ldc, int nkz, int relu)
{
  constexpr int CA = TM / 32, CB = TN / 32, SN = CA + CB;
  constexpr int WM = TM / 32, WN = TN / 32;
  __shared__ ushort_t As[NBUF * TM * 64];
  __shared__ ushort_t Bs[NBUF * TN * 64];
  const int tid = threadIdx.x, lane = tid & 63, wid = tid >> 6;
  const int wm = wid >> 1, wn = wid & 1;
  const int kz = blockIdx.z;
  const int Kz = K / nkz, k0 = kz * Kz, nt = Kz >> 6;

  const ushort_t* Ab = A + (long)blockIdx.y * TM * lda + k0;
  const ushort_t* Bb = B + (long)blockIdx.x * TN * ldb + k0;

  const ushort_t* srcA[CA]; ushort_t* ldsA[CA];
  const ushort_t* srcB[CB]; ushort_t* ldsB[CB];
#pragma unroll
  for (int c = 0; c < CA; ++c) {
    int off = c * 4096 + tid * 16;
    int row = off >> 7;
    int scol = ((off & 127) ^ ((row & 7) << 4)) >> 1;
    srcA[c] = Ab + (long)row * lda + scol;
    ldsA[c] = As + c * 2048 + wid * 512;
  }
#pragma unroll
  for (int c = 0; c < CB; ++c) {
    int off = c * 4096 + tid * 16;
    int row = off >> 7;
    int scol = ((off & 127) ^ ((row & 7) << 4)) >> 1;
    srcB[c] = Bb + (long)row * ldb + scol;
    ldsB[c] = Bs + c * 2048 + wid * 512;
  }

  f32x4 acc[WM][WN] = {};

  auto STAGE = [&](int buf, int t) {
#pragma unroll
    for (int c = 0; c < CA; ++c) gload16(srcA[c] + t * 64, ldsA[c] + buf * TM * 64);
#pragma unroll
    for (int c = 0; c < CB; ++c) gload16(srcB[c] + t * 64, ldsB[c] + buf * TN * 64);
  };

  auto COMPUTE = [&](int buf) {
#pragma unroll
    for (int ks = 0; ks < 2; ++ks) {
      const int kb = ks * 64 + ((lane >> 4) << 4);
      bf16x8 af[WM], bfr[WN];
#pragma unroll
      for (int f = 0; f < WM; ++f) {
        int ra = wm * (TM / 2) + f * 16 + (lane & 15);
        af[f] = *(const bf16x8*)((const char*)As + buf * TM * 128 + ra * 128 + (kb ^ ((ra & 7) << 4)));
      }
#pragma unroll
      for (int g = 0; g < WN; ++g) {
        int rb = wn * (TN / 2) + g * 16 + (lane & 15);
        bfr[g] = *(const bf16x8*)((const char*)Bs + buf * TN * 128 + rb * 128 + (kb ^ ((rb & 7) << 4)));
      }
      __builtin_amdgcn_s_setprio(1);
#pragma unroll
      for (int i = 0; i < WM; ++i)
#pragma unroll
        for (int j = 0; j < WN; ++j)
          acc[i][j] = __builtin_amdgcn_mfma_f32_16x16x32_bf16(af[i], bfr[j], acc[i][j], 0, 0, 0);
      __builtin_amdgcn_s_setprio(0);
    }
  };

  STAGE(0, 0);
  if constexpr (NBUF == 3) {
    STAGE(1, 1);
    for (int t = 0; t < nt; ++t) {
      if (t < nt - 1) { if constexpr (SN == 6) VWAIT(6); else VWAIT(4); }
      else VWAIT(0);
      bar();
      if (t + 2 < nt) STAGE((t + 2) % 3, t + 2);
      COMPUTE(t % 3);
    }
  } else {
    for (int t = 0; t < nt; ++t) {
      VWAIT(0);
      bar();
      if (t + 1 < nt) STAGE((t + 1) & 1, t + 1);
      COMPUTE(t & 1);
    }
  }

  const int row0 = blockIdx.y * TM + wm * (TM / 2) + ((lane >> 4) << 2);
  int col0 = blockIdx.x * TN + wn * (TN / 2) + (lane & 15);
  const float* bsel = bias;
  ushort_t* osel = outB;
  int seg = 0;
  if (EPI == 3) {
    seg = (blockIdx.x * TN) >> 11;
    if (seg == 1) { bsel = bias2; osel = outB2; }
    else if (seg == 2) { bsel = bias3; }
    col0 -= seg * 2048;
  }

  if (EPI == 3 && seg == 2) {
    // V segment: repack tile via LDS (reuse As), write vT[bh][dk][s] coalesced
    ushort_t* Vt = As;
    const int colvBase = blockIdx.x * TN - 4096;         // within V's 2048 cols
    const int rowBase = blockIdx.y * TM;
    const int h = colvBase >> 8, dk0 = colvBase & 255;
    const int bh = ((rowBase >> 8) << 3) + h;
    const int s0 = rowBase & 255;
    bar();                          // all waves done reading As
    // TN=128: two halves of 64 dk-cols (Vt = 64x136 fits in 2-buf As)
#pragma unroll
    for (int half = 0; half < 2; ++half) {
      if (half) bar();            // previous half's stores done
      if (wn == half) {
#pragma unroll
        for (int i = 0; i < WM; ++i)
#pragma unroll
          for (int j = 0; j < WN; ++j) {
            const int colL = j * 16 + (lane & 15);       // half-local [0,64)
            const float bv = bsel[col0 + j * 16];
#pragma unroll
            for (int r = 0; r < 4; ++r) {
              const int rowL = wm * 64 + i * 16 + ((lane >> 4) << 2) + r;
              Vt[colL * 136 + rowL] = f2b(acc[i][j][r] + bv);
            }
          }
      }
      bar();
      const int dkl = tid >> 2, scc = (tid & 3) * 32;
      ushort_t* dst = outB3 + ((long)bh << 16) +
                      (long)(dk0 + half * 64 + dkl) * 256 + s0 + scc;
#pragma unroll
      for (int m = 0; m < 4; ++m)
        *(u16x8*)(dst + m * 8) = *(const u16x8*)(Vt + dkl * 136 + scc + m * 8);
    }
    return;
  }

#pragma unroll
  for (int i = 0; i < WM; ++i) {
#pragma unroll
    for (int j = 0; j < WN; ++j) {
      const int col = col0 + j * 16;
      float bv = 0.f;
      if (EPI == 2) bv = (kz == 0) ? bias[col] : 0.f;
      else if (EPI == 0 || EPI == 3) bv = bsel[col];
#pragma unroll
      for (int r = 0; r < 4; ++r) {
        const int row = row0 + i * 16 + r;
        float v = acc[i][j][r] + bv;
        if (EPI == 2) {
          outF[(long)kz * 1048576 + (long)row * ldc + col] = v;
        } else if (EPI == 3) {
          // head-major: [bh][s][dk]
          const long addr = (((long)(row >> 8) * 8 + (col >> 8)) << 16) +
                            (long)(row & 255) * 256 + (col & 255);
          osel[addr] = f2b(v);
        } else {
          if (relu) v = fmaxf(v, 0.f);
          osel[(long)row * ldc + col] = f2b(v);
        }
      }
    }
  }
}

// ---------------------------------------------------------------------------
// Fused attention core: 512 blocks of 2 waves (32-row q-tile each), XCD-mapped
// so each head's 8 q-tiles stay on one XCD. 72KB LDS -> 2 blocks/CU; out-of-
// phase blocks cover each other's pipeline drains.
// Phase 1: S = Q K^T (2-phase dbuf). Phase 2: in-wave masked softmax.
// Phase 3: P -> LDS -> wave-local A-fragments. Phase 4: V^T streams through
// Bs (4 chunks of 64 dk, 2-phase); O = P V in regs -> ao.
// ---------------------------------------------------------------------------
__global__ __launch_bounds__(128, 1)
void attnf_k(const ushort_t* __restrict__ qh, const ushort_t* __restrict__ kh,
             const ushort_t* __restrict__ vT, const int* __restrict__ attnm,
             ushort_t* __restrict__ ao)
{
  __shared__ ushort_t As[2][32 * 64];     // 8KB (Q dbuf)
  __shared__ ushort_t Bs[2][256 * 64];    // 64KB (K dbuf -> P repack -> V dbuf)
  const int i = blockIdx.x;
  const int xcd = i & 7, slot = i >> 3;   // slot 0..63
  const int bh = xcd + 8 * (slot >> 3);   // 8 heads per XCD
  const int qt = slot & 7;                // 8 q-tiles of 32 rows
  const int b = bh >> 3, h = bh & 7;
  const int tid = threadIdx.x, lane = tid & 63, wid = tid >> 6;  // wid 0..1
  const int l15 = lane & 15, l4 = lane >> 4;

  unsigned mbits = 0;
#pragma unroll
  for (int j = 0; j < 16; ++j)
    mbits |= (attnm[b * 256 + j * 16 + l15] != 0 ? 1u : 0u) << j;

  const ushort_t* Qb = qh + ((long)bh << 16) + qt * 32 * 256;
  const ushort_t* Kb = kh + ((long)bh << 16);
  const ushort_t* srcA[2]; ushort_t* ldsA[2];
  const ushort_t* srcB[16]; ushort_t* ldsB[16];
#pragma unroll
  for (int c = 0; c < 2; ++c) {
    int off = c * 2048 + tid * 16;        // bytes in 4KB Q chunk (32 rows x 128B)
    int row = off >> 7;
    int scol = ((off & 127) ^ ((row & 7) << 4)) >> 1;
    srcA[c] = Qb + (long)row * 256 + scol;
    ldsA[c] = As[0] + c * 1024 + wid * 512;
  }
#pragma unroll
  for (int c = 0; c < 16; ++c) {
    int off = c * 2048 + tid * 16;        // bytes in 32KB K chunk (256 rows x 128B)
    int row = off >> 7;
    int scol = ((off & 127) ^ ((row & 7) << 4)) >> 1;
    srcB[c] = Kb + (long)row * 256 + scol;
    ldsB[c] = Bs[0] + c * 1024 + wid * 512;
  }

  auto STAGE = [&](int buf, int t) {
#pragma unroll
    for (int c = 0; c < 2; ++c) gload16(srcA[c] + t * 64, ldsA[c] + buf * 2048);
#pragma unroll
    for (int c = 0; c < 16; ++c) gload16(srcB[c] + t * 64, ldsB[c] + buf * 16384);
  };

  // ---- Phase 1: S = Q K^T ----
  f32x4 sacc[16] = {};
  STAGE(0, 0);
  for (int t = 0; t < 4; ++t) {
    VWAIT(0);
    bar();
    if (t < 3) STAGE((t + 1) & 1, t + 1);
    const int buf = t & 1;
#pragma unroll
    for (int ks = 0; ks < 2; ++ks) {
      const int kb = ks * 64 + (l4 << 4);
      const int ra = wid * 16 + l15;
      bf16x8 af = *(const bf16x8*)((const char*)As[buf] + ra * 128 + (kb ^ ((ra & 7) << 4)));
      __builtin_amdgcn_s_setprio(1);
#pragma unroll
      for (int j = 0; j < 16; ++j) {
        const int rb = j * 16 + l15;
        bf16x8 bf_ = *(const bf16x8*)((const char*)Bs[buf] + rb * 128 + (kb ^ ((rb & 7) << 4)));
        sacc[j] = __builtin_amdgcn_mfma_f32_16x16x32_bf16(af, bf_, sacc[j], 0, 0, 0);
      }
      __builtin_amdgcn_s_setprio(0);
    }
  }

  // ---- Phase 2: masked softmax (lane holds keys j*16+l15 for rows l4*4+r) ----
  float mr[4] = {-3e38f, -3e38f, -3e38f, -3e38f}, sr[4] = {};
#pragma unroll
  for (int j = 0; j < 16; ++j) {
    const bool mk = (mbits >> j) & 1;
#pragma unroll
    for (int r = 0; r < 4; ++r) {
      float s = mk ? -1e9f : sacc[j][r] * 0.0625f;
      sacc[j][r] = s;
      mr[r] = fmaxf(mr[r], s);
    }
  }
#pragma unroll
  for (int o = 1; o < 16; o <<= 1)
#pragma unroll
    for (int r = 0; r < 4; ++r) mr[r] = fmaxf(mr[r], __shfl_xor(mr[r], o, 16));
#pragma unroll
  for (int j = 0; j < 16; ++j)
#pragma unroll
    for (int r = 0; r < 4; ++r) {
      float e = __expf(sacc[j][r] - mr[r]);
      sacc[j][r] = e;
      sr[r] += e;
    }
#pragma unroll
  for (int o = 1; o < 16; o <<= 1)
#pragma unroll
    for (int r = 0; r < 4; ++r) sr[r] += __shfl_xor(sr[r], o, 16);
#pragma unroll
  for (int r = 0; r < 4; ++r) sr[r] = 1.f / sr[r];

  // ---- Phase 3: P -> LDS (own rows), read back as A-fragments ----
  ushort_t* Rp = (ushort_t*)Bs;            // 32 rows x 512B, swizzled
  bar();                                   // all waves done reading Bs (K)
#pragma unroll
  for (int j = 0; j < 16; ++j)
#pragma unroll
    for (int r = 0; r < 4; ++r) {
      const int row = wid * 16 + l4 * 4 + r;
      *(ushort_t*)((char*)Rp + row * 512 + (((j * 16 + l15) * 2) ^ ((row & 7) << 4))) =
          f2b(sacc[j][r] * sr[r]);
    }
  // wave-local read-back (rows wid*16..+15 written by this wave only)
  bf16x8 pf[8];
  {
    const int ra = wid * 16 + l15;
#pragma unroll
    for (int ks = 0; ks < 8; ++ks)
      pf[ks] = *(const bf16x8*)((const char*)Rp + ra * 512 +
                                ((ks * 64 + (l4 << 4)) ^ ((ra & 7) << 4)));
  }
  bar();                                   // P reads done; Bs free for V

  // ---- Phase 4: O = P V ; V^T streams in 4 chunks of 64 dk-rows ----
  const ushort_t* Vb = vT + ((long)bh << 16);
  int velem[16];
#pragma unroll
  for (int c = 0; c < 16; ++c) {
    int off = c * 2048 + tid * 16;         // bytes in 32KB V chunk (64 rows x 512B)
    int row = off >> 9;
    int colb = (off & 511) ^ ((row & 7) << 4);
    velem[c] = row * 256 + (colb >> 1);
  }
  auto VSTAGE = [&](int buf, int ch) {
#pragma unroll
    for (int c = 0; c < 16; ++c)
      gload16(Vb + (long)ch * 16384 + velem[c], Bs[buf] + c * 1024 + wid * 512);
  };

  f32x4 oacc[16] = {};
  VSTAGE(0, 0);
  for (int ch = 0; ch < 4; ++ch) {
    VWAIT(0);
    bar();
    if (ch < 3) VSTAGE((ch + 1) & 1, ch + 1);
    const char* vb = (const char*)Bs[ch & 1];
#pragma unroll
    for (int ks = 0; ks < 8; ++ks) {
      const int kb = ks * 64 + (l4 << 4);
      __builtin_amdgcn_s_setprio(1);
#pragma unroll
      for (int j = 0; j < 4; ++j) {
        const int rb = j * 16 + l15;
        bf16x8 vf = *(const bf16x8*)(vb + rb * 512 + (kb ^ ((rb & 7) << 4)));
        oacc[ch * 4 + j] = __builtin_amdgcn_mfma_f32_16x16x32_bf16(pf[ks], vf, oacc[ch * 4 + j], 0, 0, 0);
      }
      __builtin_amdgcn_s_setprio(0);
    }
  }

  // ---- store O -> ao[b,s][h*256+dk] ----
  const int rowq = qt * 32 + wid * 16 + (l4 << 2);
#pragma unroll
  for (int ch = 0; ch < 4; ++ch)
#pragma unroll
    for (int j = 0; j < 4; ++j) {
      const int dk = ch * 64 + j * 16 + l15;
#pragma unroll
      for (int r = 0; r < 4; ++r)
        ao[(long)(b * 256 + rowq + r) * 2048 + h * 256 + dk] = f2b(oacc[ch * 4 + j][r]);
    }
}

// x = data*sqrt(D) + pe + seg_emb[view_idx*S]
__global__ __launch_bounds__(256)
void build_x(const float* __restrict__ data, const float* __restrict__ seg,
             const int* __restrict__ viewp, float* __restrict__ x)
{
  int i = blockIdx.x * 256 + threadIdx.x;
  int d = i & 511;
  int s = (i >> 9) & 255;
  float ang = (float)s * exp2f((float)d * -0.03125f);
  float pe = (d & 1) ? cosf(ang) : sinf(ang);
  int vrow = viewp[0] * SS;
  x[i] = data[i] * 22.627416997969522f + pe + seg[vrow * DIM + d];
}

// LayerNorm with optional fused residual: x += p0+p1, write back, normalize.
__global__ __launch_bounds__(256)
void lnorm_k(const float* __restrict__ x, const float* __restrict__ parts, int np,
             float* __restrict__ xout,
             const float* __restrict__ alpha, const float* __restrict__ beta,
             ushort_t* __restrict__ outB, float* __restrict__ outF)
{
  const int row = blockIdx.x, tid = threadIdx.x;
  const long base = (long)row * DIM;
  float2 v = ((const float2*)(x + base))[tid];
  if (np) {
    for (int p = 0; p < np; ++p) {
      float2 a = ((const float2*)(parts + (long)p * 1048576 + base))[tid];
      v.x += a.x; v.y += a.y;
    }
    ((float2*)(xout + base))[tid] = v;
  }
  float s = v.x + v.y;
#pragma unroll
  for (int o = 32; o; o >>= 1) s += __shfl_xor(s, o, 64);
  __shared__ float rs[4], rq[4];
  if ((tid & 63) == 0) rs[tid >> 6] = s;
  __syncthreads();
  const float mu = (rs[0] + rs[1] + rs[2] + rs[3]) * (1.f / 512.f);
  const float dx = v.x - mu, dy = v.y - mu;
  float q = dx * dx + dy * dy;
#pragma unroll
  for (int o = 32; o; o >>= 1) q += __shfl_xor(q, o, 64);
  if ((tid & 63) == 0) rq[tid >> 6] = q;
  __syncthreads();
  const float var = (rq[0] + rq[1] + rq[2] + rq[3]) * (1.f / 511.f);
  const float rstd = 1.f / (sqrtf(var) + 1e-6f);
  const int d0 = tid * 2;
  const float o0 = alpha[d0] * dx * rstd + beta[d0];
  const float o1 = alpha[d0 + 1] * dy * rstd + beta[d0 + 1];
  if (outB) { outB[base + d0] = f2b(o0); outB[base + d0 + 1] = f2b(o1); }
  else      { outF[base + d0] = o0;      outF[base + d0 + 1] = o1; }
}

// merged weight transposes: A-group (R=512,C=2048): Wq,Wk,Wv,W1 x 4 layers
__global__ __launch_bounds__(256)
void wtransA(const float* __restrict__ Wq, const float* __restrict__ Wk,
             const float* __restrict__ Wv, const float* __restrict__ W1,
             ushort_t* __restrict__ qkvW, ushort_t* __restrict__ W1T)
{
  __shared__ float t[32][33];
  const int z = blockIdx.z, widx = z >> 2, layer = z & 3;
  const float* src = (widx == 0) ? Wq : (widx == 1) ? Wk : (widx == 2) ? Wv : W1;
  src += (long)layer * 512 * 2048;
  ushort_t* dst = (widx == 3) ? (W1T + (long)layer * 2048 * 512)
                              : (qkvW + (long)layer * (6144L * 512) + (long)widx * 2048 * 512);
  const int c0 = blockIdx.x * 32, r0 = blockIdx.y * 32;
  const int tx = threadIdx.x & 31, ty = threadIdx.x >> 5;
#pragma unroll
  for (int i = 0; i < 4; ++i) t[ty + i * 8][tx] = src[(long)(r0 + ty + i * 8) * 2048 + c0 + tx];
  __syncthreads();
#pragma unroll
  for (int i = 0; i < 4; ++i) dst[(long)(c0 + ty + i * 8) * 512 + r0 + tx] = f2b(t[tx][ty + i * 8]);
}

// merged weight transposes: B-group (R=2048,C=512): Wo,W2 x 4 layers
__global__ __launch_bounds__(256)
void wtransB(const float* __restrict__ Wo, const float* __restrict__ W2,
             ushort_t* __restrict__ WoT, ushort_t* __restrict__ W2T)
{
  __shared__ float t[32][33];
  const int z = blockIdx.z, widx = z >> 2, layer = z & 3;
  const float* src = ((widx == 0) ? Wo : W2) + (long)layer * 2048 * 512;
  ushort_t* dst = ((widx == 0) ? WoT : W2T) + (long)layer * 512 * 2048;
  const int c0 = blockIdx.x * 32, r0 = blockIdx.y * 32;
  const int tx = threadIdx.x & 31, ty = threadIdx.x >> 5;
#pragma unroll
  for (int i = 0; i < 4; ++i) t[ty + i * 8][tx] = src[(long)(r0 + ty + i * 8) * 512 + c0 + tx];
  __syncthreads();
#pragma unroll
  for (int i = 0; i < 4; ++i) dst[(long)(c0 + ty + i * 8) * 2048 + r0 + tx] = f2b(t[tx][ty + i * 8]);
}

extern "C" void kernel_launch(void* const* d_in, const int* in_sizes, int n_in,
                              void* d_out, int out_size, void* d_ws, size_t ws_size,
                              hipStream_t stream)
{
  const float* data  = (const float*)d_in[0];
  const int*   attnm = (const int*)d_in[1];
  const int*   viewp = (const int*)d_in[2];
  const float* seg   = (const float*)d_in[3];
  const float* Wq    = (const float*)d_in[4];
  const float* bq    = (const float*)d_in[5];
  const float* Wk    = (const float*)d_in[6];
  const float* bk    = (const float*)d_in[7];
  const float* Wv    = (const float*)d_in[8];
  const float* bv    = (const float*)d_in[9];
  const float* Wo    = (const float*)d_in[10];
  const float* bo    = (const float*)d_in[11];
  const float* W1    = (const float*)d_in[12];
  const float* b1    = (const float*)d_in[13];
  const float* W2    = (const float*)d_in[14];
  const float* b2    = (const float*)d_in[15];
  const float* al1   = (const float*)d_in[16];
  const float* be1   = (const float*)d_in[17];
  const float* al2   = (const float*)d_in[18];
  const float* be2   = (const float*)d_in[19];
  const float* alf   = (const float*)d_in[20];
  const float* bef   = (const float*)d_in[21];

  char* w = (char*)d_ws;
  const size_t MB = 1024 * 1024;
  ushort_t* qkvW = (ushort_t*)(w + 0 * MB);   // [L][6144][512] bf16
  ushort_t* WoT  = (ushort_t*)(w + 24 * MB);  // [L][512][2048]
  ushort_t* W1T  = (ushort_t*)(w + 32 * MB);  // [L][2048][512]
  ushort_t* W2T  = (ushort_t*)(w + 40 * MB);  // [L][512][2048]
  float*    x    = (float*)   (w + 48 * MB);  // [2048][512] fp32
  ushort_t* x2   = (ushort_t*)(w + 52 * MB);  // [2048][512] bf16
  ushort_t* qb   = (ushort_t*)(w + 54 * MB);  // [64][256][256] head-major Q
  ushort_t* kbf  = (ushort_t*)(w + 62 * MB);  // [64][256][256] head-major K
  ushort_t* vT   = (ushort_t*)(w + 70 * MB);  // [64][256][256] V^T
  ushort_t* ao   = (ushort_t*)(w + 78 * MB);  // [2048][2048]
  ushort_t* ffh  = (ushort_t*)(w + 86 * MB);  // [2048][2048]
  float*    parts= (float*)   (w + 94 * MB);  // 2 x [2048][512] fp32 (94..102)

  dim3 blk(256);
  const long QKV_L = 6144L * 512;
  wtransA<<<dim3(64, 16, 16), blk, 0, stream>>>(Wq, Wk, Wv, W1, qkvW, W1T);
  wtransB<<<dim3(16, 64, 8), blk, 0, stream>>>(Wo, W2, WoT, W2T);
  build_x<<<4096, blk, 0, stream>>>(data, seg, viewp, x);

  for (int i = 0; i < LNUM; ++i) {
    if (i == 0)
      lnorm_k<<<2048, blk, 0, stream>>>(x, nullptr, 0, nullptr, al1, be1, x2, nullptr);
    // fused QKV: [2048,512] x [6144,512]^T, 128x128 2-phase; Q,K head-major; V->vT
    gemm_bt<128, 128, 3, 2><<<dim3(48, 16, 1), blk, 0, stream>>>(
        x2, qkvW + (long)i * QKV_L, bq + i * 2048, bk + i * 2048, bv + i * 2048,
        qb, kbf, vT, nullptr, 512, 512, 512, 2048, 1, 0);
    // fused scores + softmax + PV -> ao (512 blocks x 2 waves, XCD-mapped)
    attnf_k<<<dim3(512), dim3(128), 0, stream>>>(qb, kbf, vT, attnm, ao);
    // Wo: [2048,2048] x [512,2048]^T, split-K=2 -> parts
    gemm_bt<64, 64, 2, 3><<<dim3(8, 32, 2), blk, 0, stream>>>(
        ao, WoT + (long)i * 512 * 2048, bo + i * 512, nullptr, nullptr,
        nullptr, nullptr, nullptr, parts, 2048, 2048, 2048, 512, 2, 0);
    lnorm_k<<<2048, blk, 0, stream>>>(x, parts, 2, x, al2 + i * 512, be2 + i * 512, x2, nullptr);
    // FF1: [2048,512] x [2048,512]^T, 128x64 depth-2, relu
    gemm_bt<128, 64, 0, 3><<<dim3(32, 16, 1), blk, 0, stream>>>(
        x2, W1T + (long)i * 2048 * 512, b1 + i * 2048, nullptr, nullptr,
        ffh, nullptr, nullptr, nullptr, 512, 512, 512, 2048, 1, 1);
    // FF2: [2048,2048] x [512,2048]^T, split-K=2 -> parts
    gemm_bt<64, 64, 2, 3><<<dim3(8, 32, 2), blk, 0, stream>>>(
        ffh, W2T + (long)i * 512 * 2048, b2 + i * 512, nullptr, nullptr,
        nullptr, nullptr, nullptr, parts, 2048, 2048, 2048, 512, 2, 0);
    if (i < LNUM - 1)
      lnorm_k<<<2048, blk, 0, stream>>>(x, parts, 2, x, al1 + (i + 1) * 512, be1 + (i + 1) * 512, x2, nullptr);
    else
      lnorm_k<<<2048, blk, 0, stream>>>(x, parts, 2, x, alf, bef, nullptr, (float*)d_out);
  }
}

// Round 18
// 396.415 us; speedup vs baseline: 1.0259x; 1.0259x over previous
//
#include <hip/hip_runtime.h>
#include <hip/hip_bf16.h>

#define LNUM 4
#define DIM  512
#define SS   256

typedef unsigned short ushort_t;
typedef __attribute__((ext_vector_type(8))) short bf16x8;
typedef __attribute__((ext_vector_type(4))) float f32x4;
typedef __attribute__((ext_vector_type(8))) unsigned short u16x8;

#define VWAIT(n) asm volatile("s_waitcnt vmcnt(" #n ")" ::: "memory")
#define LWAIT()  asm volatile("s_waitcnt lgkmcnt(0)" ::: "memory")
__device__ __forceinline__ void bar() { __builtin_amdgcn_s_barrier(); }

__device__ __forceinline__ ushort_t f2b(float f) {
  union { float f; unsigned u; } x; x.f = f;
  unsigned r = x.u + 0x7FFFu + ((x.u >> 16) & 1u);
  return (ushort_t)(r >> 16);
}

__device__ __forceinline__ void gload16(const void* g, void* s) {
  __builtin_amdgcn_global_load_lds((const __attribute__((address_space(1))) void*)g,
                                   (__attribute__((address_space(3))) void*)s, 16, 0, 0);
}

// ---------------------------------------------------------------------------
// C = A * B^T. NBUF=3: depth-2 prefetch, counted vmcnt. NBUF=2: 2-phase
// double-buffer (only for tiles whose grid keeps >=2 blocks/CU).
// EPI 0: outB = bf16(acc + bias) [relu opt]
// EPI 2: outF[kz partial] = acc + bias(kz==0)   (split-K fp32 stores)
// EPI 3: fused QKV routing; Q,K head-major [bh][s][dk]; V repacked -> vT
// ---------------------------------------------------------------------------
template<int TM, int TN, int EPI, int NBUF>
__global__ __launch_bounds__(256, 2)
void gemm_bt(const ushort_t* __restrict__ A, const ushort_t* __restrict__ B,
             const float* __restrict__ bias, const float* __restrict__ bias2,
             const float* __restrict__ bias3,
             ushort_t* __restrict__ outB, ushort_t* __restrict__ outB2,
             ushort_t* __restrict__ outB3, float* __restrict__ outF,
             int K, int lda, int ldb, int ldc, int nkz, int relu)
{
  constexpr int CA = TM / 32, CB = TN / 32, SN = CA + CB;
  constexpr int WM = TM / 32, WN = TN / 32;
  __shared__ ushort_t As[NBUF * TM * 64];
  __shared__ ushort_t Bs[NBUF * TN * 64];
  const int tid = threadIdx.x, lane = tid & 63, wid = tid >> 6;
  const int wm = wid >> 1, wn = wid & 1;
  const int kz = blockIdx.z;
  const int Kz = K / nkz, k0 = kz * Kz, nt = Kz >> 6;

  const ushort_t* Ab = A + (long)blockIdx.y * TM * lda + k0;
  const ushort_t* Bb = B + (long)blockIdx.x * TN * ldb + k0;

  const ushort_t* srcA[CA]; ushort_t* ldsA[CA];
  const ushort_t* srcB[CB]; ushort_t* ldsB[CB];
#pragma unroll
  for (int c = 0; c < CA; ++c) {
    int off = c * 4096 + tid * 16;
    int row = off >> 7;
    int scol = ((off & 127) ^ ((row & 7) << 4)) >> 1;
    srcA[c] = Ab + (long)row * lda + scol;
    ldsA[c] = As + c * 2048 + wid * 512;
  }
#pragma unroll
  for (int c = 0; c < CB; ++c) {
    int off = c * 4096 + tid * 16;
    int row = off >> 7;
    int scol = ((off & 127) ^ ((row & 7) << 4)) >> 1;
    srcB[c] = Bb + (long)row * ldb + scol;
    ldsB[c] = Bs + c * 2048 + wid * 512;
  }

  f32x4 acc[WM][WN] = {};

  auto STAGE = [&](int buf, int t) {
#pragma unroll
    for (int c = 0; c < CA; ++c) gload16(srcA[c] + t * 64, ldsA[c] + buf * TM * 64);
#pragma unroll
    for (int c = 0; c < CB; ++c) gload16(srcB[c] + t * 64, ldsB[c] + buf * TN * 64);
  };

  auto COMPUTE = [&](int buf) {
#pragma unroll
    for (int ks = 0; ks < 2; ++ks) {
      const int kb = ks * 64 + ((lane >> 4) << 4);
      bf16x8 af[WM], bfr[WN];
#pragma unroll
      for (int f = 0; f < WM; ++f) {
        int ra = wm * (TM / 2) + f * 16 + (lane & 15);
        af[f] = *(const bf16x8*)((const char*)As + buf * TM * 128 + ra * 128 + (kb ^ ((ra & 7) << 4)));
      }
#pragma unroll
      for (int g = 0; g < WN; ++g) {
        int rb = wn * (TN / 2) + g * 16 + (lane & 15);
        bfr[g] = *(const bf16x8*)((const char*)Bs + buf * TN * 128 + rb * 128 + (kb ^ ((rb & 7) << 4)));
      }
      __builtin_amdgcn_s_setprio(1);
#pragma unroll
      for (int i = 0; i < WM; ++i)
#pragma unroll
        for (int j = 0; j < WN; ++j)
          acc[i][j] = __builtin_amdgcn_mfma_f32_16x16x32_bf16(af[i], bfr[j], acc[i][j], 0, 0, 0);
      __builtin_amdgcn_s_setprio(0);
    }
  };

  STAGE(0, 0);
  if constexpr (NBUF == 3) {
    STAGE(1, 1);
    for (int t = 0; t < nt; ++t) {
      if (t < nt - 1) { if constexpr (SN == 6) VWAIT(6); else VWAIT(4); }
      else VWAIT(0);
      bar();
      if (t + 2 < nt) STAGE((t + 2) % 3, t + 2);
      COMPUTE(t % 3);
    }
  } else {
    for (int t = 0; t < nt; ++t) {
      VWAIT(0);
      bar();
      if (t + 1 < nt) STAGE((t + 1) & 1, t + 1);
      COMPUTE(t & 1);
    }
  }

  const int row0 = blockIdx.y * TM + wm * (TM / 2) + ((lane >> 4) << 2);
  int col0 = blockIdx.x * TN + wn * (TN / 2) + (lane & 15);
  const float* bsel = bias;
  ushort_t* osel = outB;
  int seg = 0;
  if (EPI == 3) {
    seg = (blockIdx.x * TN) >> 11;
    if (seg == 1) { bsel = bias2; osel = outB2; }
    else if (seg == 2) { bsel = bias3; }
    col0 -= seg * 2048;
  }

  if (EPI == 3 && seg == 2) {
    // V segment: repack tile via LDS (reuse As), write vT[bh][dk][s] coalesced
    ushort_t* Vt = As;
    const int colvBase = blockIdx.x * TN - 4096;         // within V's 2048 cols
    const int rowBase = blockIdx.y * TM;
    const int h = colvBase >> 8, dk0 = colvBase & 255;
    const int bh = ((rowBase >> 8) << 3) + h;
    const int s0 = rowBase & 255;
    bar();                          // all waves done reading As
    // TN=128: two halves of 64 dk-cols (Vt = 64x136 fits in 2-buf As)
#pragma unroll
    for (int half = 0; half < 2; ++half) {
      if (half) bar();            // previous half's stores done
      if (wn == half) {
#pragma unroll
        for (int i = 0; i < WM; ++i)
#pragma unroll
          for (int j = 0; j < WN; ++j) {
            const int colL = j * 16 + (lane & 15);       // half-local [0,64)
            const float bv = bsel[col0 + j * 16];
#pragma unroll
            for (int r = 0; r < 4; ++r) {
              const int rowL = wm * 64 + i * 16 + ((lane >> 4) << 2) + r;
              Vt[colL * 136 + rowL] = f2b(acc[i][j][r] + bv);
            }
          }
      }
      bar();
      const int dkl = tid >> 2, scc = (tid & 3) * 32;
      ushort_t* dst = outB3 + ((long)bh << 16) +
                      (long)(dk0 + half * 64 + dkl) * 256 + s0 + scc;
#pragma unroll
      for (int m = 0; m < 4; ++m)
        *(u16x8*)(dst + m * 8) = *(const u16x8*)(Vt + dkl * 136 + scc + m * 8);
    }
    return;
  }

#pragma unroll
  for (int i = 0; i < WM; ++i) {
#pragma unroll
    for (int j = 0; j < WN; ++j) {
      const int col = col0 + j * 16;
      float bv = 0.f;
      if (EPI == 2) bv = (kz == 0) ? bias[col] : 0.f;
      else if (EPI == 0 || EPI == 3) bv = bsel[col];
#pragma unroll
      for (int r = 0; r < 4; ++r) {
        const int row = row0 + i * 16 + r;
        float v = acc[i][j][r] + bv;
        if (EPI == 2) {
          outF[(long)kz * 1048576 + (long)row * ldc + col] = v;
        } else if (EPI == 3) {
          // head-major: [bh][s][dk]
          const long addr = (((long)(row >> 8) * 8 + (col >> 8)) << 16) +
                            (long)(row & 255) * 256 + (col & 255);
          osel[addr] = f2b(v);
        } else {
          if (relu) v = fmaxf(v, 0.f);
          osel[(long)row * ldc + col] = f2b(v);
        }
      }
    }
  }
}

// ---------------------------------------------------------------------------
// Fused attention core: block = (head, 64-row q-tile); 4 waves, 80KB LDS
// (2 blocks/CU). Phase 1: S = Q K^T (2-phase dbuf); at the final QK step the
// dead Bs[0] receives a V-chunk-0 prefetch. Phase 2: in-wave masked softmax
// (loads in flight). Phase 3: P -> Bs[1] -> wave-local A-fragments, explicit
// lgkm drain, single counted vm drain. Phase 4: V^T streams (2-phase).
// ---------------------------------------------------------------------------
__global__ __launch_bounds__(256, 2)
void attnf_k(const ushort_t* __restrict__ qh, const ushort_t* __restrict__ kh,
             const ushort_t* __restrict__ vT, const int* __restrict__ attnm,
             ushort_t* __restrict__ ao)
{
  __shared__ ushort_t As[2][64 * 64];     // 16KB (Q dbuf)
  __shared__ ushort_t Bs[2][256 * 64];    // 64KB (K dbuf -> P in Bs[1] -> V dbuf)
  const int bh = blockIdx.x, qt = blockIdx.y;
  const int b = bh >> 3, h = bh & 7;
  const int tid = threadIdx.x, lane = tid & 63, wid = tid >> 6;
  const int l15 = lane & 15, l4 = lane >> 4;

  unsigned mbits = 0;
#pragma unroll
  for (int j = 0; j < 16; ++j)
    mbits |= (attnm[b * 256 + j * 16 + l15] != 0 ? 1u : 0u) << j;

  const ushort_t* Qb = qh + ((long)bh << 16) + qt * 64 * 256;
  const ushort_t* Kb = kh + ((long)bh << 16);
  const ushort_t* srcA[2]; ushort_t* ldsA[2];
  const ushort_t* srcB[8]; ushort_t* ldsB[8];
#pragma unroll
  for (int c = 0; c < 2; ++c) {
    int off = c * 4096 + tid * 16;
    int row = off >> 7;
    int scol = ((off & 127) ^ ((row & 7) << 4)) >> 1;
    srcA[c] = Qb + (long)row * 256 + scol;
    ldsA[c] = As[0] + c * 2048 + wid * 512;
  }
#pragma unroll
  for (int c = 0; c < 8; ++c) {
    int off = c * 4096 + tid * 16;
    int row = off >> 7;
    int scol = ((off & 127) ^ ((row & 7) << 4)) >> 1;
    srcB[c] = Kb + (long)row * 256 + scol;
    ldsB[c] = Bs[0] + c * 2048 + wid * 512;
  }

  auto STAGE = [&](int buf, int t) {
#pragma unroll
    for (int c = 0; c < 2; ++c) gload16(srcA[c] + t * 64, ldsA[c] + buf * 4096);
#pragma unroll
    for (int c = 0; c < 8; ++c) gload16(srcB[c] + t * 64, ldsB[c] + buf * 16384);
  };

  // V source offsets (64 dk-rows x 256 keys per chunk; 512B rows, swizzled)
  const ushort_t* Vb = vT + ((long)bh << 16);
  int velem[8];
#pragma unroll
  for (int c = 0; c < 8; ++c) {
    int off = c * 4096 + tid * 16;
    int row = off >> 9;
    int colb = (off & 511) ^ ((row & 7) << 4);
    velem[c] = row * 256 + (colb >> 1);
  }
  auto VSTAGE = [&](int buf, int ch) {
#pragma unroll
    for (int c = 0; c < 8; ++c)
      gload16(Vb + (long)ch * 16384 + velem[c], Bs[buf] + c * 2048 + wid * 512);
  };

  // ---- Phase 1: S = Q K^T ; V chunk 0 prefetched at the last step ----
  f32x4 sacc[16] = {};
  STAGE(0, 0);
  for (int t = 0; t < 4; ++t) {
    VWAIT(0);
    bar();
    if (t < 3) STAGE((t + 1) & 1, t + 1);
    else       VSTAGE(0, 0);             // Bs[0] dead at t=3 (reads from Bs[1])
    const int buf = t & 1;
#pragma unroll
    for (int ks = 0; ks < 2; ++ks) {
      const int kb = ks * 64 + (l4 << 4);
      const int ra = wid * 16 + l15;
      bf16x8 af = *(const bf16x8*)((const char*)As[buf] + ra * 128 + (kb ^ ((ra & 7) << 4)));
      __builtin_amdgcn_s_setprio(1);
#pragma unroll
      for (int j = 0; j < 16; ++j) {
        const int rb = j * 16 + l15;
        bf16x8 bf_ = *(const bf16x8*)((const char*)Bs[buf] + rb * 128 + (kb ^ ((rb & 7) << 4)));
        sacc[j] = __builtin_amdgcn_mfma_f32_16x16x32_bf16(af, bf_, sacc[j], 0, 0, 0);
      }
      __builtin_amdgcn_s_setprio(0);
    }
  }

  // ---- Phase 2: masked softmax (V chunk 0 loads in flight) ----
  float mr[4] = {-3e38f, -3e38f, -3e38f, -3e38f}, sr[4] = {};
#pragma unroll
  for (int j = 0; j < 16; ++j) {
    const bool mk = (mbits >> j) & 1;
#pragma unroll
    for (int r = 0; r < 4; ++r) {
      float s = mk ? -1e9f : sacc[j][r] * 0.0625f;
      sacc[j][r] = s;
      mr[r] = fmaxf(mr[r], s);
    }
  }
#pragma unroll
  for (int o = 1; o < 16; o <<= 1)
#pragma unroll
    for (int r = 0; r < 4; ++r) mr[r] = fmaxf(mr[r], __shfl_xor(mr[r], o, 16));
#pragma unroll
  for (int j = 0; j < 16; ++j)
#pragma unroll
    for (int r = 0; r < 4; ++r) {
      float e = __expf(sacc[j][r] - mr[r]);
      sacc[j][r] = e;
      sr[r] += e;
    }
#pragma unroll
  for (int o = 1; o < 16; o <<= 1)
#pragma unroll
    for (int r = 0; r < 4; ++r) sr[r] += __shfl_xor(sr[r], o, 16);
#pragma unroll
  for (int r = 0; r < 4; ++r) sr[r] = 1.f / sr[r];

  // ---- Phase 3: P -> Bs[1] (K reads done), read back wave-local ----
  bar();                                   // all waves finished reading Bs[1]
  ushort_t* Rp = (ushort_t*)Bs[1];
#pragma unroll
  for (int j = 0; j < 16; ++j)
#pragma unroll
    for (int r = 0; r < 4; ++r) {
      const int row = wid * 16 + l4 * 4 + r;
      *(ushort_t*)((char*)Rp + row * 512 + (((j * 16 + l15) * 2) ^ ((row & 7) << 4))) =
          f2b(sacc[j][r] * sr[r]);
    }
  bf16x8 pf[8];
  {
    const int ra = wid * 16 + l15;
#pragma unroll
    for (int ks = 0; ks < 8; ++ks)
      pf[ks] = *(const bf16x8*)((const char*)Rp + ra * 512 +
                                ((ks * 64 + (l4 << 4)) ^ ((ra & 7) << 4)));
  }
  LWAIT();                                 // pf ds_reads complete before release
  VWAIT(0);                                // V chunk 0 landed
  bar();                                   // block-wide: chunk0 ready, P consumed

  // ---- Phase 4: O = P V ; chunks: 0->Bs[0] (ready), 1->Bs[1], 2->Bs[0], 3->Bs[1]
  f32x4 oacc[16] = {};
  for (int ch = 0; ch < 4; ++ch) {
    if (ch) { VWAIT(0); bar(); }
    if (ch < 3) VSTAGE((ch + 1) & 1, ch + 1);
    const char* vb = (const char*)Bs[ch & 1];
#pragma unroll
    for (int ks = 0; ks < 8; ++ks) {
      const int kb = ks * 64 + (l4 << 4);
      __builtin_amdgcn_s_setprio(1);
#pragma unroll
      for (int j = 0; j < 4; ++j) {
        const int rb = j * 16 + l15;
        bf16x8 vf = *(const bf16x8*)(vb + rb * 512 + (kb ^ ((rb & 7) << 4)));
        oacc[ch * 4 + j] = __builtin_amdgcn_mfma_f32_16x16x32_bf16(pf[ks], vf, oacc[ch * 4 + j], 0, 0, 0);
      }
      __builtin_amdgcn_s_setprio(0);
    }
  }

  // ---- store O -> ao[b,s][h*256+dk] ----
  const int rowq = qt * 64 + wid * 16 + (l4 << 2);
#pragma unroll
  for (int ch = 0; ch < 4; ++ch)
#pragma unroll
    for (int j = 0; j < 4; ++j) {
      const int dk = ch * 64 + j * 16 + l15;
#pragma unroll
      for (int r = 0; r < 4; ++r)
        ao[(long)(b * 256 + rowq + r) * 2048 + h * 256 + dk] = f2b(oacc[ch * 4 + j][r]);
    }
}

// fused: x = data*sqrt(D)+pe+seg  AND  x2 = lnorm(x) bf16 (first layer input)
__global__ __launch_bounds__(256)
void build_ln(const float* __restrict__ data, const float* __restrict__ seg,
              const int* __restrict__ viewp,
              const float* __restrict__ alpha, const float* __restrict__ beta,
              float* __restrict__ x, ushort_t* __restrict__ x2)
{
  const int row = blockIdx.x, tid = threadIdx.x;
  const long base = (long)row * DIM;
  const int s = row & 255;
  const int vrow = viewp[0] * SS;
  const int d0 = tid * 2;
  float2 v;
  {
    float2 dv = ((const float2*)(data + base))[tid];
    float a0 = (float)s * exp2f((float)d0 * -0.03125f);
    float a1 = (float)s * exp2f((float)(d0 + 1) * -0.03125f);
    float pe0 = (d0 & 1) ? cosf(a0) : sinf(a0);
    float pe1 = ((d0 + 1) & 1) ? cosf(a1) : sinf(a1);
    v.x = dv.x * 22.627416997969522f + pe0 + seg[vrow * DIM + d0];
    v.y = dv.y * 22.627416997969522f + pe1 + seg[vrow * DIM + d0 + 1];
    ((float2*)(x + base))[tid] = v;
  }
  float sm = v.x + v.y;
#pragma unroll
  for (int o = 32; o; o >>= 1) sm += __shfl_xor(sm, o, 64);
  __shared__ float rs[4], rq[4];
  if ((tid & 63) == 0) rs[tid >> 6] = sm;
  __syncthreads();
  const float mu = (rs[0] + rs[1] + rs[2] + rs[3]) * (1.f / 512.f);
  const float dx = v.x - mu, dy = v.y - mu;
  float q = dx * dx + dy * dy;
#pragma unroll
  for (int o = 32; o; o >>= 1) q += __shfl_xor(q, o, 64);
  if ((tid & 63) == 0) rq[tid >> 6] = q;
  __syncthreads();
  const float var = (rq[0] + rq[1] + rq[2] + rq[3]) * (1.f / 511.f);
  const float rstd = 1.f / (sqrtf(var) + 1e-6f);
  x2[base + d0]     = f2b(alpha[d0] * dx * rstd + beta[d0]);
  x2[base + d0 + 1] = f2b(alpha[d0 + 1] * dy * rstd + beta[d0 + 1]);
}

// LayerNorm with optional fused residual: x += p0+p1, write back, normalize.
__global__ __launch_bounds__(256)
void lnorm_k(const float* __restrict__ x, const float* __restrict__ parts, int np,
             float* __restrict__ xout,
             const float* __restrict__ alpha, const float* __restrict__ beta,
             ushort_t* __restrict__ outB, float* __restrict__ outF)
{
  const int row = blockIdx.x, tid = threadIdx.x;
  const long base = (long)row * DIM;
  float2 v = ((const float2*)(x + base))[tid];
  if (np) {
    for (int p = 0; p < np; ++p) {
      float2 a = ((const float2*)(parts + (long)p * 1048576 + base))[tid];
      v.x += a.x; v.y += a.y;
    }
    ((float2*)(xout + base))[tid] = v;
  }
  float s = v.x + v.y;
#pragma unroll
  for (int o = 32; o; o >>= 1) s += __shfl_xor(s, o, 64);
  __shared__ float rs[4], rq[4];
  if ((tid & 63) == 0) rs[tid >> 6] = s;
  __syncthreads();
  const float mu = (rs[0] + rs[1] + rs[2] + rs[3]) * (1.f / 512.f);
  const float dx = v.x - mu, dy = v.y - mu;
  float q = dx * dx + dy * dy;
#pragma unroll
  for (int o = 32; o; o >>= 1) q += __shfl_xor(q, o, 64);
  if ((tid & 63) == 0) rq[tid >> 6] = q;
  __syncthreads();
  const float var = (rq[0] + rq[1] + rq[2] + rq[3]) * (1.f / 511.f);
  const float rstd = 1.f / (sqrtf(var) + 1e-6f);
  const int d0 = tid * 2;
  const float o0 = alpha[d0] * dx * rstd + beta[d0];
  const float o1 = alpha[d0 + 1] * dy * rstd + beta[d0 + 1];
  if (outB) { outB[base + d0] = f2b(o0); outB[base + d0 + 1] = f2b(o1); }
  else      { outF[base + d0] = o0;      outF[base + d0 + 1] = o1; }
}

// merged weight transposes: A-group (R=512,C=2048): Wq,Wk,Wv,W1 x 4 layers
__global__ __launch_bounds__(256)
void wtransA(const float* __restrict__ Wq, const float* __restrict__ Wk,
             const float* __restrict__ Wv, const float* __restrict__ W1,
             ushort_t* __restrict__ qkvW, ushort_t* __restrict__ W1T)
{
  __shared__ float t[32][33];
  const int z = blockIdx.z, widx = z >> 2, layer = z & 3;
  const float* src = (widx == 0) ? Wq : (widx == 1) ? Wk : (widx == 2) ? Wv : W1;
  src += (long)layer * 512 * 2048;
  ushort_t* dst = (widx == 3) ? (W1T + (long)layer * 2048 * 512)
                              : (qkvW + (long)layer * (6144L * 512) + (long)widx * 2048 * 512);
  const int c0 = blockIdx.x * 32, r0 = blockIdx.y * 32;
  const int tx = threadIdx.x & 31, ty = threadIdx.x >> 5;
#pragma unroll
  for (int i = 0; i < 4; ++i) t[ty + i * 8][tx] = src[(long)(r0 + ty + i * 8) * 2048 + c0 + tx];
  __syncthreads();
#pragma unroll
  for (int i = 0; i < 4; ++i) dst[(long)(c0 + ty + i * 8) * 512 + r0 + tx] = f2b(t[tx][ty + i * 8]);
}

// merged weight transposes: B-group (R=2048,C=512): Wo,W2 x 4 layers
__global__ __launch_bounds__(256)
void wtransB(const float* __restrict__ Wo, const float* __restrict__ W2,
             ushort_t* __restrict__ WoT, ushort_t* __restrict__ W2T)
{
  __shared__ float t[32][33];
  const int z = blockIdx.z, widx = z >> 2, layer = z & 3;
  const float* src = ((widx == 0) ? Wo : W2) + (long)layer * 2048 * 512;
  ushort_t* dst = ((widx == 0) ? WoT : W2T) + (long)layer * 512 * 2048;
  const int c0 = blockIdx.x * 32, r0 = blockIdx.y * 32;
  const int tx = threadIdx.x & 31, ty = threadIdx.x >> 5;
#pragma unroll
  for (int i = 0; i < 4; ++i) t[ty + i * 8][tx] = src[(long)(r0 + ty + i * 8) * 512 + c0 + tx];
  __syncthreads();
#pragma unroll
  for (int i = 0; i < 4; ++i) dst[(long)(c0 + ty + i * 8) * 2048 + r0 + tx] = f2b(t[tx][ty + i * 8]);
}

extern "C" void kernel_launch(void* const* d_in, const int* in_sizes, int n_in,
                              void* d_out, int out_size, void* d_ws, size_t ws_size,
                              hipStream_t stream)
{
  const float* data  = (const float*)d_in[0];
  const int*   attnm = (const int*)d_in[1];
  const int*   viewp = (const int*)d_in[2];
  const float* seg   = (const float*)d_in[3];
  const float* Wq    = (const float*)d_in[4];
  const float* bq    = (const float*)d_in[5];
  const float* Wk    = (const float*)d_in[6];
  const float* bk    = (const float*)d_in[7];
  const float* Wv    = (const float*)d_in[8];
  const float* bv    = (const float*)d_in[9];
  const float* Wo    = (const float*)d_in[10];
  const float* bo    = (const float*)d_in[11];
  const float* W1    = (const float*)d_in[12];
  const float* b1    = (const float*)d_in[13];
  const float* W2    = (const float*)d_in[14];
  const float* b2    = (const float*)d_in[15];
  const float* al1   = (const float*)d_in[16];
  const float* be1   = (const float*)d_in[17];
  const float* al2   = (const float*)d_in[18];
  const float* be2   = (const float*)d_in[19];
  const float* alf   = (const float*)d_in[20];
  const float* bef   = (const float*)d_in[21];

  char* w = (char*)d_ws;
  const size_t MB = 1024 * 1024;
  ushort_t* qkvW = (ushort_t*)(w + 0 * MB);   // [L][6144][512] bf16
  ushort_t* WoT  = (ushort_t*)(w + 24 * MB);  // [L][512][2048]
  ushort_t* W1T  = (ushort_t*)(w + 32 * MB);  // [L][2048][512]
  ushort_t* W2T  = (ushort_t*)(w + 40 * MB);  // [L][512][2048]
  float*    x    = (float*)   (w + 48 * MB);  // [2048][512] fp32
  ushort_t* x2   = (ushort_t*)(w + 52 * MB);  // [2048][512] bf16
  ushort_t* qb   = (ushort_t*)(w + 54 * MB);  // [64][256][256] head-major Q
  ushort_t* kbf  = (ushort_t*)(w + 62 * MB);  // [64][256][256] head-major K
  ushort_t* vT   = (ushort_t*)(w + 70 * MB);  // [64][256][256] V^T
  ushort_t* ao   = (ushort_t*)(w + 78 * MB);  // [2048][2048]
  ushort_t* ffh  = (ushort_t*)(w + 86 * MB);  // [2048][2048]
  float*    parts= (float*)   (w + 94 * MB);  // 2 x [2048][512] fp32 (94..102)

  dim3 blk(256);
  const long QKV_L = 6144L * 512;
  wtransA<<<dim3(64, 16, 16), blk, 0, stream>>>(Wq, Wk, Wv, W1, qkvW, W1T);
  wtransB<<<dim3(16, 64, 8), blk, 0, stream>>>(Wo, W2, WoT, W2T);
  build_ln<<<2048, blk, 0, stream>>>(data, seg, viewp, al1, be1, x, x2);

  for (int i = 0; i < LNUM; ++i) {
    // fused QKV: [2048,512] x [6144,512]^T, 128x128 2-phase; Q,K head-major; V->vT
    gemm_bt<128, 128, 3, 2><<<dim3(48, 16, 1), blk, 0, stream>>>(
        x2, qkvW + (long)i * QKV_L, bq + i * 2048, bk + i * 2048, bv + i * 2048,
        qb, kbf, vT, nullptr, 512, 512, 512, 2048, 1, 0);
    // fused scores + softmax + PV -> ao
    attnf_k<<<dim3(64, 4), blk, 0, stream>>>(qb, kbf, vT, attnm, ao);
    // Wo: [2048,2048] x [512,2048]^T, split-K=2 -> parts
    gemm_bt<64, 64, 2, 3><<<dim3(8, 32, 2), blk, 0, stream>>>(
        ao, WoT + (long)i * 512 * 2048, bo + i * 512, nullptr, nullptr,
        nullptr, nullptr, nullptr, parts, 2048, 2048, 2048, 512, 2, 0);
    lnorm_k<<<2048, blk, 0, stream>>>(x, parts, 2, x, al2 + i * 512, be2 + i * 512, x2, nullptr);
    // FF1: [2048,512] x [2048,512]^T, 128x64 depth-2, relu
    gemm_bt<128, 64, 0, 3><<<dim3(32, 16, 1), blk, 0, stream>>>(
        x2, W1T + (long)i * 2048 * 512, b1 + i * 2048, nullptr, nullptr,
        ffh, nullptr, nullptr, nullptr, 512, 512, 512, 2048, 1, 1);
    // FF2: [2048,2048] x [512,2048]^T, split-K=2 -> parts
    gemm_bt<64, 64, 2, 3><<<dim3(8, 32, 2), blk, 0, stream>>>(
        ffh, W2T + (long)i * 512 * 2048, b2 + i * 512, nullptr, nullptr,
        nullptr, nullptr, nullptr, parts, 2048, 2048, 2048, 512, 2, 0);
    if (i < LNUM - 1)
      lnorm_k<<<2048, blk, 0, stream>>>(x, parts, 2, x, al1 + (i + 1) * 512, be1 + (i + 1) * 512, x2, nullptr);
    else
      lnorm_k<<<2048, blk, 0, stream>>>(x, parts, 2, x, alf, bef, nullptr, (float*)d_out);
  }
}